// Round 2
// baseline (402.957 us; speedup 1.0000x reference)
//
#include <hip/hip_runtime.h>
#include <math.h>

constexpr int D_DIM = 2048;
constexpr int N_EXP = 64;
constexpr int ROWS  = 64;          // rows per block
constexpr int KC    = 32;          // k-chunk staged in LDS
constexpr int NCH   = D_DIM / KC;  // 64 chunks

// 512 threads = 8 waves. Wave w -> experts 8w..8w+7 (W in SGPRs via uniform
// addressing). Lane l -> row l. x staged global->LDS double-buffered, padded
// [64][33] so the 64-lane column read is a free 2-way bank alias.
__global__ __launch_bounds__(512, 2) void topk_router_kernel(
    const float* __restrict__ x, const float* __restrict__ W,
    float* __restrict__ outProbs, float* __restrict__ outIdx,
    float* __restrict__ outWt)
{
    __shared__ float Lx[2][ROWS][KC + 1];       // ~16.9 KB
    __shared__ float Llog[ROWS][N_EXP + 1];     // ~16.6 KB
    __shared__ float Lmax[ROWS], Lsum[ROWS];

    const int t    = threadIdx.x;
    const int lane = t & 63;
    const int wave = t >> 6;                                    // 0..7
    const int eBase = __builtin_amdgcn_readfirstlane(wave * 8); // uniform -> SGPR
    const int rowBase = blockIdx.x * ROWS;

    // staging map: thread t loads 16B of row (t>>3) at k-offset (t&7)*4
    const int srow = t >> 3;
    const int sk   = (t & 7) * 4;

    const float* xrow = x + (size_t)(rowBase + srow) * D_DIM + sk;
    const float* Wu   = W + (size_t)eBase * D_DIM;   // uniform pointer -> s_load

    // prologue: stage chunk 0
    {
        const float4 p = *(const float4*)xrow;
        float* dst = &Lx[0][srow][sk];
        dst[0] = p.x; dst[1] = p.y; dst[2] = p.z; dst[3] = p.w;
    }

    float acc[8] = {0.f,0.f,0.f,0.f,0.f,0.f,0.f,0.f};

    for (int c = 0; c < NCH; ++c) {
        const int cur = c & 1;
        __syncthreads();                  // Lx[cur] visible; prior reads of Lx[cur^1] done

        float4 nf;
        const bool more = (c + 1 < NCH);
        if (more) nf = *(const float4*)(xrow + (c + 1) * KC);   // overlaps compute

        const int kb = c * KC;
#pragma unroll
        for (int k4 = 0; k4 < KC; k4 += 4) {
            float w4[8][4];               // uniform values -> SGPRs
#pragma unroll
            for (int j = 0; j < 8; ++j)
                *(float4*)w4[j] = *(const float4*)(Wu + j * D_DIM + kb + k4);
#pragma unroll
            for (int kk = 0; kk < 4; ++kk) {
                const float xv = Lx[cur][lane][k4 + kk];        // 2-way alias = free
#pragma unroll
                for (int j = 0; j < 8; ++j)
                    acc[j] = fmaf(xv, w4[j][kk], acc[j]);       // v_fmac v,s,v
            }
        }

        if (more) {                       // write next buffer (no conflict with readers)
            float* dst = &Lx[cur ^ 1][srow][sk];
            dst[0] = nf.x; dst[1] = nf.y; dst[2] = nf.z; dst[3] = nf.w;
        }
    }

    // scatter logits: row=lane, experts eBase..eBase+7
#pragma unroll
    for (int j = 0; j < 8; ++j) Llog[lane][eBase + j] = acc[j];
    __syncthreads();

    // wave 0: one lane per row -> top-2 + softmax denom + small outputs
    if (t < ROWS) {
        const int r = t;
        float v1 = Llog[r][0]; int i1 = 0;
        float v2 = -INFINITY;  int i2 = 0;
        for (int e = 1; e < N_EXP; ++e) {        // strict > : lower index wins ties
            const float v = Llog[r][e];
            if (v > v1)      { v2 = v1; i2 = i1; v1 = v; i1 = e; }
            else if (v > v2) { v2 = v;  i2 = e; }
        }
        float S = 0.f;
        for (int e = 0; e < N_EXP; ++e) S += expf(Llog[r][e] - v1);
        Lmax[r] = v1; Lsum[r] = S;

        const float p1 = 1.0f / S;               // exp(v1-v1)/S
        const float p2 = expf(v2 - v1) / S;
        const float den = p1 + p2 + 1e-9f;
        const int row = rowBase + r;
        outIdx[row * 2 + 0] = (float)i1;
        outIdx[row * 2 + 1] = (float)i2;
        outWt [row * 2 + 0] = p1 / den;
        outWt [row * 2 + 1] = p2 / den;
    }
    __syncthreads();

    // probs: 64 rows x 16 float4-slots = 1024 slots; 512 threads x 2, coalesced
    {
        const int s0 = t, s1 = t + 512;
        int ss[2] = {s0, s1};
#pragma unroll
        for (int u = 0; u < 2; ++u) {
            const int s  = ss[u];
            const int r  = s >> 4;
            const int e0 = (s & 15) * 4;
            const float m  = Lmax[r];
            const float rS = 1.0f / Lsum[r];
            float4 p;
            p.x = expf(Llog[r][e0 + 0] - m) * rS;
            p.y = expf(Llog[r][e0 + 1] - m) * rS;
            p.z = expf(Llog[r][e0 + 2] - m) * rS;
            p.w = expf(Llog[r][e0 + 3] - m) * rS;
            *(float4*)(outProbs + (size_t)(rowBase + r) * N_EXP + e0) = p;
        }
    }
}

extern "C" void kernel_launch(void* const* d_in, const int* in_sizes, int n_in,
                              void* d_out, int out_size, void* d_ws, size_t ws_size,
                              hipStream_t stream) {
    const float* x = (const float*)d_in[0];
    const float* W = (const float*)d_in[1];
    const int nRows = in_sizes[0] / D_DIM;               // 16384

    float* outProbs = (float*)d_out;                     // nRows*64
    float* outIdx   = outProbs + (size_t)nRows * N_EXP;  // nRows*2 (float-cast ints)
    float* outWt    = outIdx   + (size_t)nRows * 2;      // nRows*2

    dim3 grid(nRows / ROWS), block(512);
    topk_router_kernel<<<grid, block, 0, stream>>>(x, W, outProbs, outIdx, outWt);
}

// Round 3
// 230.566 us; speedup vs baseline: 1.7477x; 1.7477x over previous
//
#include <hip/hip_runtime.h>
#include <math.h>

constexpr int D_DIM = 2048;
constexpr int N_EXP = 64;
constexpr int ROWS  = 64;          // rows per block
constexpr int KC    = 32;          // k per staged chunk
constexpr int KW    = 256;         // k range per wave (D/8 waves)
constexpr int NCH   = KW / KC;     // 8 chunks per wave
constexpr int PADT  = 68;          // padded leading dim (16B-aligned, bank-spread)

// 512 threads = 8 waves. Waves split K (256 each) over the same 64x64 tile.
// Per-wave private LDS staging (transposed), 8x8 fp32 register tile per lane,
// deterministic cross-wave reduction in LDS, then top-2 + softmax epilogue.
__global__ __launch_bounds__(512, 2) void topk_router_kernel(
    const float* __restrict__ x, const float* __restrict__ W,
    float* __restrict__ outProbs, float* __restrict__ outIdx,
    float* __restrict__ outWt)
{
    __shared__ __align__(16) float Stage[8][2][KC][PADT]; // 139,264 B (also reused as scratch)
    __shared__ __align__(16) float Llog[ROWS][PADT];      // 17,408 B
    __shared__ float Lmax[ROWS], Lv2[ROWS];
    __shared__ int   Li1[ROWS], Li2[ROWS];

    const int t    = threadIdx.x;
    const int lane = t & 63;
    const int wave = t >> 6;
    const int rowBase = blockIdx.x * ROWS;

    const int r0 = (lane >> 3) * 8;      // 8 rows per lane
    const int e0 = (lane & 7) * 8;       // 8 experts per lane
    const int srow = lane >> 3;          // staging: sub-row
    const int scol = (lane & 7) * 4;     // staging: float4 column

    float (*xT)[PADT] = Stage[wave][0];  // [k][row]
    float (*wT)[PADT] = Stage[wave][1];  // [k][expert]

    const int kw0 = wave * KW;
    const float* xg = x + (size_t)rowBase * D_DIM + kw0 + scol;
    const float* wg = W + (size_t)kw0 + scol;

    // ---- prologue: prefetch chunk 0 into registers ----
    float4 px[8], pw[8];
#pragma unroll
    for (int f = 0; f < 8; ++f) {
        const int rr = f * 8 + srow;
        px[f] = *(const float4*)(xg + (size_t)rr * D_DIM);
        pw[f] = *(const float4*)(wg + (size_t)rr * D_DIM);
    }

    float acc[8][8];
#pragma unroll
    for (int i = 0; i < 8; ++i)
#pragma unroll
        for (int j = 0; j < 8; ++j) acc[i][j] = 0.f;

    for (int c = 0; c < NCH; ++c) {
        __syncthreads();                          // prior chunk's LDS reads complete
        // staged regs -> LDS (transposed)
#pragma unroll
        for (int f = 0; f < 8; ++f) {
            const int rr = f * 8 + srow;
            xT[scol + 0][rr] = px[f].x; xT[scol + 1][rr] = px[f].y;
            xT[scol + 2][rr] = px[f].z; xT[scol + 3][rr] = px[f].w;
            wT[scol + 0][rr] = pw[f].x; wT[scol + 1][rr] = pw[f].y;
            wT[scol + 2][rr] = pw[f].z; wT[scol + 3][rr] = pw[f].w;
        }
        __syncthreads();

        // prefetch next chunk (completes under ~4096 cyc of FMA below)
        if (c + 1 < NCH) {
            const int kb = (c + 1) * KC;
#pragma unroll
            for (int f = 0; f < 8; ++f) {
                const int rr = f * 8 + srow;
                px[f] = *(const float4*)(xg + (size_t)rr * D_DIM + kb);
                pw[f] = *(const float4*)(wg + (size_t)rr * D_DIM + kb);
            }
        }

        // compute: per k, 4x ds_read_b128 -> 64 FMA
#pragma unroll 8
        for (int k = 0; k < KC; ++k) {
            const float4 xa = *(const float4*)&xT[k][r0];
            const float4 xb = *(const float4*)&xT[k][r0 + 4];
            const float4 wa = *(const float4*)&wT[k][e0];
            const float4 wb = *(const float4*)&wT[k][e0 + 4];
            const float xr[8] = {xa.x, xa.y, xa.z, xa.w, xb.x, xb.y, xb.z, xb.w};
            const float wc[8] = {wa.x, wa.y, wa.z, wa.w, wb.x, wb.y, wb.z, wb.w};
#pragma unroll
            for (int i = 0; i < 8; ++i)
#pragma unroll
                for (int j = 0; j < 8; ++j)
                    acc[i][j] = fmaf(xr[i], wc[j], acc[i][j]);
        }
    }

    // ---- partials -> own wave's staging region (reused as scratch, stride 68) ----
    float* scratch = (float*)Stage[wave];         // 4352 floats; need 63*68+63 < 4352
#pragma unroll
    for (int i = 0; i < 8; ++i) {
        const float4 a = {acc[i][0], acc[i][1], acc[i][2], acc[i][3]};
        const float4 b = {acc[i][4], acc[i][5], acc[i][6], acc[i][7]};
        *(float4*)(scratch + (r0 + i) * PADT + e0)     = a;
        *(float4*)(scratch + (r0 + i) * PADT + e0 + 4) = b;
    }
    __syncthreads();

    // ---- deterministic 8-way reduction: thread t sums row t>>3, experts (t&7)*8.. ----
    const int rr = t >> 3;
    const int ee = (t & 7) * 8;
    float4 sa = {0.f, 0.f, 0.f, 0.f}, sb = {0.f, 0.f, 0.f, 0.f};
#pragma unroll
    for (int w = 0; w < 8; ++w) {
        const float* sc = (const float*)Stage[w] + rr * PADT + ee;
        const float4 a = *(const float4*)sc;
        const float4 b = *(const float4*)(sc + 4);
        sa.x += a.x; sa.y += a.y; sa.z += a.z; sa.w += a.w;
        sb.x += b.x; sb.y += b.y; sb.z += b.z; sb.w += b.w;
    }
    *(float4*)&Llog[rr][ee]     = sa;
    *(float4*)&Llog[rr][ee + 4] = sb;
    __syncthreads();

    // ---- top-2 scan: one thread per row (strict > : lower index wins ties) ----
    if (t < ROWS) {
        const int r = t;
        float v1 = Llog[r][0]; int i1 = 0;
        float v2 = -INFINITY;  int i2 = 0;
        for (int e = 1; e < N_EXP; ++e) {
            const float v = Llog[r][e];
            if (v > v1)      { v2 = v1; i2 = i1; v1 = v; i1 = e; }
            else if (v > v2) { v2 = v;  i2 = e; }
        }
        Lmax[r] = v1; Lv2[r] = v2; Li1[r] = i1; Li2[r] = i2;
    }
    __syncthreads();

    // ---- softmax + outputs: each thread exps its own 8 logits (still in regs) ----
    {
        const float m = Lmax[rr];
        float e8[8];
        e8[0] = __expf(sa.x - m); e8[1] = __expf(sa.y - m);
        e8[2] = __expf(sa.z - m); e8[3] = __expf(sa.w - m);
        e8[4] = __expf(sb.x - m); e8[5] = __expf(sb.y - m);
        e8[6] = __expf(sb.z - m); e8[7] = __expf(sb.w - m);
        float S = e8[0] + e8[1] + e8[2] + e8[3] + e8[4] + e8[5] + e8[6] + e8[7];
        // row sum across the 8 lanes sharing rr (lanes g*8..g*8+7)
        S += __shfl_xor(S, 1, 64);
        S += __shfl_xor(S, 2, 64);
        S += __shfl_xor(S, 4, 64);
        const float rS = 1.0f / S;

        float4 pa = {e8[0] * rS, e8[1] * rS, e8[2] * rS, e8[3] * rS};
        float4 pb = {e8[4] * rS, e8[5] * rS, e8[6] * rS, e8[7] * rS};
        const int row = rowBase + rr;
        *(float4*)(outProbs + (size_t)row * N_EXP + ee)     = pa;
        *(float4*)(outProbs + (size_t)row * N_EXP + ee + 4) = pb;

        if ((t & 7) == 0) {
            const float p1 = rS;                       // exp(v1-v1)*rS
            const float p2 = __expf(Lv2[rr] - m) * rS;
            const float den = p1 + p2 + 1e-9f;
            outIdx[row * 2 + 0] = (float)Li1[rr];
            outIdx[row * 2 + 1] = (float)Li2[rr];
            outWt [row * 2 + 0] = p1 / den;
            outWt [row * 2 + 1] = p2 / den;
        }
    }
}

extern "C" void kernel_launch(void* const* d_in, const int* in_sizes, int n_in,
                              void* d_out, int out_size, void* d_ws, size_t ws_size,
                              hipStream_t stream) {
    const float* x = (const float*)d_in[0];
    const float* W = (const float*)d_in[1];
    const int nRows = in_sizes[0] / D_DIM;               // 16384

    float* outProbs = (float*)d_out;                     // nRows*64
    float* outIdx   = outProbs + (size_t)nRows * N_EXP;  // nRows*2 (float-cast ints)
    float* outWt    = outIdx   + (size_t)nRows * 2;      // nRows*2

    dim3 grid(nRows / ROWS), block(512);
    topk_router_kernel<<<grid, block, 0, stream>>>(x, W, outProbs, outIdx, outWt);
}

// Round 4
// 196.031 us; speedup vs baseline: 2.0556x; 1.1762x over previous
//
#include <hip/hip_runtime.h>
#include <math.h>

typedef _Float16 f16x8 __attribute__((ext_vector_type(8)));
typedef _Float16 f16x4 __attribute__((ext_vector_type(4)));
typedef float    f32x16 __attribute__((ext_vector_type(16)));

constexpr int D_DIM = 2048;
constexpr int N_EXP = 64;
constexpr int BM    = 32;        // rows per block
constexpr int KW    = 512;       // K-range per wave (D/4)
constexpr int KC    = 32;        // K per staged chunk
constexpr int NCH   = KW / KC;   // 16
constexpr int XST   = 40;        // fp16 row stride (80 B: 16B-aligned rows, bank-uniform)
constexpr int PWB   = 15360;     // per-wave LDS bytes: X1(2560)+X2(2560)+W1(5120)+W2(5120)

// 256 threads = 4 waves. Waves split K; each wave computes a full 32x64 fp32
// partial via split-fp16 MFMA (x = x1 + x2/2048 exact-ish; 3 combo passes into
// 2 accumulator groups). No barriers in the main loop (per-wave LDS).
__global__ __launch_bounds__(256, 2) void topk_router_kernel(
    const float* __restrict__ x, const float* __restrict__ Wm,
    float* __restrict__ outProbs, float* __restrict__ outIdx,
    float* __restrict__ outWt)
{
    __shared__ __align__(16) char LDSB[4 * PWB];   // 61,440 B -> 2 blocks/CU

    const int t    = threadIdx.x;
    const int lane = t & 63;
    const int wave = t >> 6;
    const int rowBase = blockIdx.x * BM;

    char* base = LDSB + wave * PWB;
    _Float16 (*X1)[XST] = (_Float16(*)[XST])(base);           // [32][40]
    _Float16 (*X2)[XST] = (_Float16(*)[XST])(base + 2560);
    _Float16 (*W1)[XST] = (_Float16(*)[XST])(base + 5120);    // [64][40]
    _Float16 (*W2)[XST] = (_Float16(*)[XST])(base + 10240);

    const int k0   = wave * KW;
    const int srow = lane >> 3;          // 0..7
    const int sc4  = (lane & 7) * 4;     // k-offset within chunk (float/fp16 idx)

    const float* xg = x  + (size_t)(rowBase + srow) * D_DIM + k0 + sc4;
    const float* wg = Wm + (size_t)srow * D_DIM + k0 + sc4;

    // prologue: prefetch chunk 0 (coalesced: 8 lanes x 16B = 128B per row-group)
    float4 px[4], pw[8];
#pragma unroll
    for (int f = 0; f < 4; ++f) px[f] = *(const float4*)(xg + (size_t)(8 * f) * D_DIM);
#pragma unroll
    for (int f = 0; f < 8; ++f) pw[f] = *(const float4*)(wg + (size_t)(8 * f) * D_DIM);

    f32x16 acc0[2], acc1[2];
#pragma unroll
    for (int n = 0; n < 2; ++n)
#pragma unroll
        for (int i = 0; i < 16; ++i) { acc0[n][i] = 0.f; acc1[n][i] = 0.f; }

    const int fr = lane & 31;            // frag non-k index (row / expert)
    const int fg = (lane >> 5) * 8;      // frag k-group offset

    for (int ch = 0; ch < NCH; ++ch) {
        // ---- split-convert staged regs -> LDS fp16 pairs ----
#pragma unroll
        for (int f = 0; f < 4; ++f) {
            const int r = srow + 8 * f;
            f16x4 h1, h2;
            h1[0] = (_Float16)px[f].x; h1[1] = (_Float16)px[f].y;
            h1[2] = (_Float16)px[f].z; h1[3] = (_Float16)px[f].w;
            h2[0] = (_Float16)((px[f].x - (float)h1[0]) * 2048.f);
            h2[1] = (_Float16)((px[f].y - (float)h1[1]) * 2048.f);
            h2[2] = (_Float16)((px[f].z - (float)h1[2]) * 2048.f);
            h2[3] = (_Float16)((px[f].w - (float)h1[3]) * 2048.f);
            *(f16x4*)&X1[r][sc4] = h1;
            *(f16x4*)&X2[r][sc4] = h2;
        }
#pragma unroll
        for (int f = 0; f < 8; ++f) {
            const int e = srow + 8 * f;
            f16x4 h1, h2;
            h1[0] = (_Float16)pw[f].x; h1[1] = (_Float16)pw[f].y;
            h1[2] = (_Float16)pw[f].z; h1[3] = (_Float16)pw[f].w;
            h2[0] = (_Float16)((pw[f].x - (float)h1[0]) * 2048.f);
            h2[1] = (_Float16)((pw[f].y - (float)h1[1]) * 2048.f);
            h2[2] = (_Float16)((pw[f].z - (float)h1[2]) * 2048.f);
            h2[3] = (_Float16)((pw[f].w - (float)h1[3]) * 2048.f);
            *(f16x4*)&W1[e][sc4] = h1;
            *(f16x4*)&W2[e][sc4] = h2;
        }

        // ---- issue next-chunk global loads (hidden under MFMA below) ----
        if (ch + 1 < NCH) {
            const int kb = (ch + 1) * KC;
#pragma unroll
            for (int f = 0; f < 4; ++f)
                px[f] = *(const float4*)(xg + (size_t)(8 * f) * D_DIM + kb);
#pragma unroll
            for (int f = 0; f < 8; ++f)
                pw[f] = *(const float4*)(wg + (size_t)(8 * f) * D_DIM + kb);
        }

        // ---- MFMA: 2 k-steps x (6 b128 reads + 6 mfma) ----
#pragma unroll
        for (int ks = 0; ks < 2; ++ks) {
            const int ko = ks * 16 + fg;
            const f16x8 A1 = *(const f16x8*)&X1[fr][ko];
            const f16x8 A2 = *(const f16x8*)&X2[fr][ko];
#pragma unroll
            for (int n = 0; n < 2; ++n) {
                const f16x8 B1 = *(const f16x8*)&W1[n * 32 + fr][ko];
                const f16x8 B2 = *(const f16x8*)&W2[n * 32 + fr][ko];
                acc0[n] = __builtin_amdgcn_mfma_f32_32x32x16_f16(A1, B1, acc0[n], 0, 0, 0);
                acc1[n] = __builtin_amdgcn_mfma_f32_32x32x16_f16(A1, B2, acc1[n], 0, 0, 0);
                acc1[n] = __builtin_amdgcn_mfma_f32_32x32x16_f16(A2, B1, acc1[n], 0, 0, 0);
            }
        }
    }

    // ---- combine groups, write per-wave partials to scratch (reuse staging) ----
    float* scr = (float*)base;            // 32 x 68 floats = 8704 B <= 15360
    const float S2 = 1.0f / 2048.0f;
#pragma unroll
    for (int n = 0; n < 2; ++n)
#pragma unroll
        for (int rg = 0; rg < 16; ++rg) {
            const int row = (rg & 3) + 8 * (rg >> 2) + 4 * (lane >> 5);  // verified C layout
            const int col = n * 32 + fr;
            scr[row * 68 + col] = acc0[n][rg] + acc1[n][rg] * S2;
        }
    __syncthreads();

    // ---- deterministic 4-way reduce: thread t -> row t>>3, experts (t&7)*8.. ----
    const int r  = t >> 3;
    const int e0 = (t & 7) * 8;
    float lg[8];
#pragma unroll
    for (int j = 0; j < 8; ++j) lg[j] = 0.f;
#pragma unroll
    for (int w = 0; w < 4; ++w) {
        const float* s = (const float*)(LDSB + w * PWB) + r * 68 + e0;
        const float4 a = *(const float4*)s;
        const float4 b = *(const float4*)(s + 4);
        lg[0] += a.x; lg[1] += a.y; lg[2] += a.z; lg[3] += a.w;
        lg[4] += b.x; lg[5] += b.y; lg[6] += b.z; lg[7] += b.w;
    }

    // local top-2 (ascending j => lower index wins ties)
    float v1 = lg[0]; int i1 = e0; float v2 = -INFINITY; int i2 = 0;
#pragma unroll
    for (int j = 1; j < 8; ++j) {
        const float v = lg[j]; const int id = e0 + j;
        if (v > v1)      { v2 = v1; i2 = i1; v1 = v; i1 = id; }
        else if (v > v2) { v2 = v;  i2 = id; }
    }
    // butterfly merge across the 8 lanes sharing this row
#pragma unroll
    for (int m = 1; m < 8; m <<= 1) {
        const float ov1 = __shfl_xor(v1, m, 64); const int oi1 = __shfl_xor(i1, m, 64);
        const float ov2 = __shfl_xor(v2, m, 64); const int oi2 = __shfl_xor(i2, m, 64);
        float n1, n2; int ni1, ni2;
        const bool o1_wins = (ov1 > v1) || (ov1 == v1 && oi1 < i1);
        if (o1_wins) {
            n1 = ov1; ni1 = oi1;
            const bool a1_beats_o2 = (v1 > ov2) || (v1 == ov2 && i1 < oi2);
            if (a1_beats_o2) { n2 = v1;  ni2 = i1;  } else { n2 = ov2; ni2 = oi2; }
        } else {
            n1 = v1; ni1 = i1;
            const bool o1_beats_a2 = (ov1 > v2) || (ov1 == v2 && oi1 < i2);
            if (o1_beats_a2) { n2 = ov1; ni2 = oi1; } else { n2 = v2;  ni2 = i2;  }
        }
        v1 = n1; i1 = ni1; v2 = n2; i2 = ni2;
    }

    // softmax
    float ee[8]; float S = 0.f;
#pragma unroll
    for (int j = 0; j < 8; ++j) { ee[j] = __expf(lg[j] - v1); S += ee[j]; }
    S += __shfl_xor(S, 1, 64);
    S += __shfl_xor(S, 2, 64);
    S += __shfl_xor(S, 4, 64);
    const float rS = 1.0f / S;

    const int row = rowBase + r;
    float4 pa = {ee[0] * rS, ee[1] * rS, ee[2] * rS, ee[3] * rS};
    float4 pb = {ee[4] * rS, ee[5] * rS, ee[6] * rS, ee[7] * rS};
    *(float4*)(outProbs + (size_t)row * N_EXP + e0)     = pa;
    *(float4*)(outProbs + (size_t)row * N_EXP + e0 + 4) = pb;

    if ((t & 7) == 0) {
        const float p1 = rS;                      // exp(v1-v1)*rS
        const float p2 = __expf(v2 - v1) * rS;
        const float den = p1 + p2 + 1e-9f;
        outIdx[row * 2 + 0] = (float)i1;
        outIdx[row * 2 + 1] = (float)i2;
        outWt [row * 2 + 0] = p1 / den;
        outWt [row * 2 + 1] = p2 / den;
    }
}

extern "C" void kernel_launch(void* const* d_in, const int* in_sizes, int n_in,
                              void* d_out, int out_size, void* d_ws, size_t ws_size,
                              hipStream_t stream) {
    const float* x = (const float*)d_in[0];
    const float* W = (const float*)d_in[1];
    const int nRows = in_sizes[0] / D_DIM;               // 16384

    float* outProbs = (float*)d_out;                     // nRows*64
    float* outIdx   = outProbs + (size_t)nRows * N_EXP;  // nRows*2 (float-cast ints)
    float* outWt    = outIdx   + (size_t)nRows * 2;      // nRows*2

    dim3 grid(nRows / BM), block(256);
    topk_router_kernel<<<grid, block, 0, stream>>>(x, W, outProbs, outIdx, outWt);
}